// Round 3
// baseline (1737.717 us; speedup 1.0000x reference)
//
#include <hip/hip_runtime.h>

#define T_STEPS 256
#define B_ROWS  1024
#define NX_ 256
#define NY_ 64
#define NU_ 64
#define ND_ 32

#define CHUNK   32
#define NCHUNK  8          // T_STEPS / CHUNK

typedef _Float16 half8 __attribute__((ext_vector_type(8)));
typedef float    f32x4 __attribute__((ext_vector_type(4)));

#define MFMA16(a,b,c) __builtin_amdgcn_mfma_f32_16x16x32_f16((a),(b),(c),0,0,0)

#define XPITCH 264              // padded LDS row pitch (halfs)
#define XBUFSZ (16*XPITCH)

// Barrier that only drains LDS ops (lgkmcnt). Global stores/loads stay in
// flight across it — they have no cross-wave consumers. This removes the
// compiler's vmcnt(0) store-drain from the per-step critical path.
#define LDSBAR() asm volatile("s_waitcnt lgkmcnt(0)\n\ts_barrier" ::: "memory")

__device__ __forceinline__ half8 cvt8(f32x4 a, f32x4 b) {
  half8 h;
  h[0]=(_Float16)a[0]; h[1]=(_Float16)a[1]; h[2]=(_Float16)a[2]; h[3]=(_Float16)a[3];
  h[4]=(_Float16)b[0]; h[5]=(_Float16)b[1]; h[6]=(_Float16)b[2]; h[7]=(_Float16)b[3];
  return h;
}

// ---------------------------------------------------------------------------
// dst = src @ src (256x256 f32, row-major). Broadcast A-row, coalesced B-col.
// ---------------------------------------------------------------------------
extern "C" __global__ __launch_bounds__(256)
void matsq(const float* __restrict__ src, float* __restrict__ dst)
{
  const int r = blockIdx.x, c = threadIdx.x;
  const float* ar = src + r*NX_;
  float a0=0.f,a1=0.f,a2=0.f,a3=0.f;
  for (int k = 0; k < NX_; k += 4) {
    a0 = fmaf(ar[k  ], src[(k  )*NX_ + c], a0);
    a1 = fmaf(ar[k+1], src[(k+1)*NX_ + c], a1);
    a2 = fmaf(ar[k+2], src[(k+2)*NX_ + c], a2);
    a3 = fmaf(ar[k+3], src[(k+3)*NX_ + c], a3);
  }
  dst[r*NX_ + c] = (a0+a1)+(a2+a3);
}

// ---------------------------------------------------------------------------
// Phase 1: per (row-group, chunk) scan from zero state (chunk 0: from x0).
// Stores only the chunk-final state (f32) to Lend[chunk][B][NX].
// ---------------------------------------------------------------------------
extern "C" __global__ __launch_bounds__(512, 4)
void phase1(const float* __restrict__ x0,
            const float* __restrict__ U,
            const float* __restrict__ Dd,
            const float* __restrict__ Wx,
            const float* __restrict__ bx,
            const float* __restrict__ Wu,
            const float* __restrict__ bu,
            const float* __restrict__ Wd,
            const float* __restrict__ bd,
            float* __restrict__ Lend)
{
  __shared__ __align__(16) _Float16 xb[2*XBUFSZ];

  const int tid  = threadIdx.x;
  const int lane = tid & 63;
  const int w    = tid >> 6;
  const int q    = lane >> 4;
  const int n16  = lane & 15;
  const int b0   = blockIdx.x * 16;
  const int ck   = blockIdx.y;          // chunk 0..6
  const int t0   = ck * CHUNK;
  const int c0   = w * 32;

  if (ck == 0) {
    int row = tid >> 5, ch = tid & 31;
    const float* s = x0 + (size_t)(b0+row)*NX_ + ch*8;
    _Float16* dst = &xb[row*XPITCH + ch*8];
    #pragma unroll
    for (int j=0;j<8;j++) dst[j] = (_Float16)s[j];
  } else {
    for (int i = tid; i < XBUFSZ; i += 512) xb[i] = (_Float16)0.f;
  }

  half8 Wh[2][8], Wl[2][8];
  #pragma unroll
  for (int nt=0; nt<2; nt++) {
    const int row = c0 + nt*16 + n16;
    #pragma unroll
    for (int kk=0; kk<8; kk++) {
      const float* s = Wx + row*NX_ + kk*32 + q*8;
      half8 h, l;
      #pragma unroll
      for (int j=0;j<8;j++){
        float v = s[j];
        _Float16 hi = (_Float16)v;
        h[j] = hi;
        l[j] = (_Float16)(v - (float)hi);
      }
      Wh[nt][kk]=h; Wl[nt][kk]=l;
    }
  }
  half8 WuF[2][2];
  #pragma unroll
  for (int nt=0;nt<2;nt++){
    const int row=c0+nt*16+n16;
    #pragma unroll
    for(int kk=0;kk<2;kk++){
      const float* s=Wu+row*NU_+kk*32+q*8; half8 h;
      #pragma unroll
      for(int j=0;j<8;j++) h[j]=(_Float16)s[j];
      WuF[nt][kk]=h;
    }
  }
  half8 WdF[2];
  #pragma unroll
  for(int nt=0;nt<2;nt++){
    const int row=c0+nt*16+n16;
    const float* s=Wd+row*ND_+q*8; half8 h;
    #pragma unroll
    for(int j=0;j<8;j++) h[j]=(_Float16)s[j];
    WdF[nt]=h;
  }
  const float bxs[2] = { bx[c0+n16], bx[c0+16+n16] };
  const float bus[2] = { bu[c0+n16], bu[c0+16+n16] };
  const float bds[2] = { bd[c0+n16], bd[c0+16+n16] };

  float xcv[2][4];
  #pragma unroll
  for(int nt=0;nt<2;nt++)
    #pragma unroll
    for(int r=0;r<4;r++)
      xcv[nt][r] = (ck==0) ? x0[(size_t)(b0+q*4+r)*NX_ + c0+nt*16+n16] : 0.f;

  // prefetch u/d for first step
  f32x4 pu0a,pu0b,pu1a,pu1b,pd0a,pd0b;
  {
    const float* usrc = U  + ((size_t)t0*B_ROWS + b0 + n16)*NU_;
    const float* dsrc = Dd + ((size_t)t0*B_ROWS + b0 + n16)*ND_;
    pu0a = *(const f32x4*)(usrc + q*8);
    pu0b = *(const f32x4*)(usrc + q*8 + 4);
    pu1a = *(const f32x4*)(usrc + 32 + q*8);
    pu1b = *(const f32x4*)(usrc + 32 + q*8 + 4);
    pd0a = *(const f32x4*)(dsrc + q*8);
    pd0b = *(const f32x4*)(dsrc + q*8 + 4);
  }

  __syncthreads();

  for (int tt=0; tt<CHUNK; tt++) {
    const _Float16* xr = xb + (tt&1)*XBUFSZ;
    _Float16*       xw = xb + ((tt&1)^1)*XBUFSZ;

    f32x4 xn[2];
    xn[0] = (f32x4){bxs[0],bxs[0],bxs[0],bxs[0]};
    xn[1] = (f32x4){bxs[1],bxs[1],bxs[1],bxs[1]};
    #pragma unroll
    for (int kk=0;kk<8;kk++){
      half8 xa = *(const half8*)(xr + n16*XPITCH + kk*32 + q*8);
      xn[0] = MFMA16(xa, Wh[0][kk], xn[0]);
      xn[1] = MFMA16(xa, Wh[1][kk], xn[1]);
      xn[0] = MFMA16(xa, Wl[0][kk], xn[0]);
      xn[1] = MFMA16(xa, Wl[1][kk], xn[1]);
    }

    half8 uf0 = cvt8(pu0a,pu0b), uf1 = cvt8(pu1a,pu1b), df = cvt8(pd0a,pd0b);

    // prefetch next step's u/d (survives the LDS-only barrier)
    {
      int tn = t0 + tt + 1; if (tn > T_STEPS-1) tn = T_STEPS-1;
      const float* un = U  + ((size_t)tn*B_ROWS + b0 + n16)*NU_;
      const float* dn = Dd + ((size_t)tn*B_ROWS + b0 + n16)*ND_;
      pu0a = *(const f32x4*)(un + q*8);
      pu0b = *(const f32x4*)(un + q*8 + 4);
      pu1a = *(const f32x4*)(un + 32 + q*8);
      pu1b = *(const f32x4*)(un + 32 + q*8 + 4);
      pd0a = *(const f32x4*)(dn + q*8);
      pd0b = *(const f32x4*)(dn + q*8 + 4);
    }

    f32x4 fu[2], fd[2];
    fu[0] = (f32x4){bus[0],bus[0],bus[0],bus[0]};
    fu[1] = (f32x4){bus[1],bus[1],bus[1],bus[1]};
    fd[0] = (f32x4){bds[0],bds[0],bds[0],bds[0]};
    fd[1] = (f32x4){bds[1],bds[1],bds[1],bds[1]};
    fu[0] = MFMA16(uf0, WuF[0][0], fu[0]);  fu[0] = MFMA16(uf1, WuF[0][1], fu[0]);
    fu[1] = MFMA16(uf0, WuF[1][0], fu[1]);  fu[1] = MFMA16(uf1, WuF[1][1], fu[1]);
    fd[0] = MFMA16(df,  WdF[0],    fd[0]);
    fd[1] = MFMA16(df,  WdF[1],    fd[1]);

    #pragma unroll
    for (int nt=0;nt<2;nt++){
      #pragma unroll
      for (int r=0;r<4;r++){
        float z = xn[nt][r] + fu[nt][r] + fd[nt][r];
        xw[(q*4+r)*XPITCH + c0+nt*16+n16] = (_Float16)z;
        xcv[nt][r] = z;
      }
    }
    LDSBAR();
  }

  float* dst = Lend + (size_t)ck*(B_ROWS*NX_);
  #pragma unroll
  for (int nt=0;nt<2;nt++)
    #pragma unroll
    for (int r=0;r<4;r++)
      dst[(size_t)(b0+q*4+r)*NX_ + c0+nt*16+n16] = xcv[nt][r];
}

// ---------------------------------------------------------------------------
// Combine: S[0] = Lend[0]; S[k-1] = S[k-2] @ P + Lend[k-1], k = 2..7.
// P = M^32 = (Wx^32)^T given as G = Wx^32 row-major: P[k][n] = G[n][k].
// ---------------------------------------------------------------------------
extern "C" __global__ __launch_bounds__(512)
void combine(const float* __restrict__ G,
             const float* __restrict__ Lend,
             float* __restrict__ S)
{
  __shared__ __align__(16) _Float16 xb[2*XBUFSZ];

  const int tid  = threadIdx.x;
  const int lane = tid & 63;
  const int w    = tid >> 6;
  const int q    = lane >> 4;
  const int n16  = lane & 15;
  const int b0   = blockIdx.x * 16;
  const int c0   = w * 32;
  const size_t BN = (size_t)B_ROWS*NX_;

  // B-frag element (n, k) = P[k][n] = G[n*NX_ + k]  (coalesced per lane)
  half8 Ph[2][8], Pl[2][8];
  #pragma unroll
  for (int nt=0; nt<2; nt++) {
    const int n = c0 + nt*16 + n16;
    #pragma unroll
    for (int kk=0; kk<8; kk++) {
      const float* s = G + (size_t)n*NX_ + kk*32 + q*8;
      half8 h, l;
      #pragma unroll
      for (int j=0;j<8;j++){
        float v = s[j];
        _Float16 hi = (_Float16)v;
        h[j] = hi;
        l[j] = (_Float16)(v - (float)hi);
      }
      Ph[nt][kk]=h; Pl[nt][kk]=l;
    }
  }

  {
    int row = tid >> 5, ch = tid & 31;
    const float* s = Lend + (size_t)(b0+row)*NX_ + ch*8;
    float*       o = S    + (size_t)(b0+row)*NX_ + ch*8;
    _Float16* dst = &xb[row*XPITCH + ch*8];
    #pragma unroll
    for (int j=0;j<8;j++){ float v = s[j]; dst[j] = (_Float16)v; o[j] = v; }
  }
  __syncthreads();

  for (int k=2; k<=7; k++) {
    const int rp = (k-2)&1;
    const _Float16* xr = xb + rp*XBUFSZ;
    _Float16*       xw = xb + (rp^1)*XBUFSZ;

    const float* lsrc = Lend + (size_t)(k-1)*BN;
    f32x4 xn[2];
    #pragma unroll
    for (int nt=0;nt<2;nt++)
      #pragma unroll
      for (int r=0;r<4;r++)
        xn[nt][r] = lsrc[(size_t)(b0+q*4+r)*NX_ + c0+nt*16+n16];

    #pragma unroll
    for (int kk=0;kk<8;kk++){
      half8 xa = *(const half8*)(xr + n16*XPITCH + kk*32 + q*8);
      xn[0] = MFMA16(xa, Ph[0][kk], xn[0]);
      xn[1] = MFMA16(xa, Ph[1][kk], xn[1]);
      xn[0] = MFMA16(xa, Pl[0][kk], xn[0]);
      xn[1] = MFMA16(xa, Pl[1][kk], xn[1]);
    }

    float* sdst = S + (size_t)(k-1)*BN;
    #pragma unroll
    for (int nt=0;nt<2;nt++)
      #pragma unroll
      for (int r=0;r<4;r++){
        float z = xn[nt][r];
        sdst[(size_t)(b0+q*4+r)*NX_ + c0+nt*16+n16] = z;
        xw[(q*4+r)*XPITCH + c0+nt*16+n16] = (_Float16)z;
      }
    __syncthreads();
  }
}

// ---------------------------------------------------------------------------
// Phase 2: full work per chunk from correct init state.
// ---------------------------------------------------------------------------
extern "C" __global__ __launch_bounds__(512, 4)
void phase2(const float* __restrict__ x0,
            const float* __restrict__ U,
            const float* __restrict__ Dd,
            const float* __restrict__ Wx,
            const float* __restrict__ bx,
            const float* __restrict__ Wu,
            const float* __restrict__ bu,
            const float* __restrict__ Wd,
            const float* __restrict__ bd,
            const float* __restrict__ Wy,
            const float* __restrict__ by,
            const float* __restrict__ S,
            float* __restrict__ Xout,
            float* __restrict__ Yout,
            float* __restrict__ Rout)
{
  __shared__ __align__(16) _Float16 xb[2*XBUFSZ];
  __shared__ __align__(16) _Float16 wyl[64*XPITCH];
  __shared__ float red[64];

  const int tid  = threadIdx.x;
  const int lane = tid & 63;
  const int w    = tid >> 6;
  const int q    = lane >> 4;
  const int n16  = lane & 15;
  const int b0   = blockIdx.x * 16;
  const int ck   = blockIdx.y;
  const int t0   = ck * CHUNK;
  const int c0   = w * 32;

  const float* init = (ck==0) ? x0 : (S + (size_t)(ck-1)*B_ROWS*NX_);

  for (int i = tid; i < 64*32; i += 512) {
    int row = i >> 5, ch = i & 31;
    const float* s = Wy + row*NX_ + ch*8;
    _Float16* dst = &wyl[row*XPITCH + ch*8];
    #pragma unroll
    for (int j=0;j<8;j++) dst[j] = (_Float16)s[j];
  }
  {
    int row = tid >> 5, ch = tid & 31;
    const float* s = init + (size_t)(b0+row)*NX_ + ch*8;
    _Float16* dst = &xb[row*XPITCH + ch*8];
    #pragma unroll
    for (int j=0;j<8;j++) dst[j] = (_Float16)s[j];
  }

  half8 Wh[2][8], Wl[2][8];
  #pragma unroll
  for (int nt=0; nt<2; nt++) {
    const int row = c0 + nt*16 + n16;
    #pragma unroll
    for (int kk=0; kk<8; kk++) {
      const float* s = Wx + row*NX_ + kk*32 + q*8;
      half8 h, l;
      #pragma unroll
      for (int j=0;j<8;j++){
        float v = s[j];
        _Float16 hi = (_Float16)v;
        h[j] = hi;
        l[j] = (_Float16)(v - (float)hi);
      }
      Wh[nt][kk]=h; Wl[nt][kk]=l;
    }
  }
  half8 WuF[2][2];
  #pragma unroll
  for (int nt=0;nt<2;nt++){
    const int row=c0+nt*16+n16;
    #pragma unroll
    for(int kk=0;kk<2;kk++){
      const float* s=Wu+row*NU_+kk*32+q*8; half8 h;
      #pragma unroll
      for(int j=0;j<8;j++) h[j]=(_Float16)s[j];
      WuF[nt][kk]=h;
    }
  }
  half8 WdF[2];
  #pragma unroll
  for(int nt=0;nt<2;nt++){
    const int row=c0+nt*16+n16;
    const float* s=Wd+row*ND_+q*8; half8 h;
    #pragma unroll
    for(int j=0;j<8;j++) h[j]=(_Float16)s[j];
    WdF[nt]=h;
  }
  const float bxs[2] = { bx[c0+n16], bx[c0+16+n16] };
  const float bus[2] = { bu[c0+n16], bu[c0+16+n16] };
  const float bds[2] = { bd[c0+n16], bd[c0+16+n16] };
  const float bys    = (w<4) ? by[w*16+n16] : 0.f;

  float xcv[2][4];
  #pragma unroll
  for(int nt=0;nt<2;nt++)
    #pragma unroll
    for(int r=0;r<4;r++)
      xcv[nt][r] = init[(size_t)(b0+q*4+r)*NX_ + c0+nt*16+n16];

  float st[7];
  #pragma unroll
  for(int i=0;i<7;i++) st[i]=0.f;

  f32x4 pu0a,pu0b,pu1a,pu1b,pd0a,pd0b;
  {
    const float* usrc = U  + ((size_t)t0*B_ROWS + b0 + n16)*NU_;
    const float* dsrc = Dd + ((size_t)t0*B_ROWS + b0 + n16)*ND_;
    pu0a = *(const f32x4*)(usrc + q*8);
    pu0b = *(const f32x4*)(usrc + q*8 + 4);
    pu1a = *(const f32x4*)(usrc + 32 + q*8);
    pu1b = *(const f32x4*)(usrc + 32 + q*8 + 4);
    pd0a = *(const f32x4*)(dsrc + q*8);
    pd0b = *(const f32x4*)(dsrc + q*8 + 4);
  }

  __syncthreads();

  for (int tt=0; tt<CHUNK; tt++) {
    const int t = t0 + tt;
    const _Float16* xr = xb + (tt&1)*XBUFSZ;
    _Float16*       xw = xb + ((tt&1)^1)*XBUFSZ;

    f32x4 xn[2];
    xn[0] = (f32x4){bxs[0],bxs[0],bxs[0],bxs[0]};
    xn[1] = (f32x4){bxs[1],bxs[1],bxs[1],bxs[1]};
    #pragma unroll
    for (int kk=0;kk<8;kk++){
      half8 xa = *(const half8*)(xr + n16*XPITCH + kk*32 + q*8);
      xn[0] = MFMA16(xa, Wh[0][kk], xn[0]);
      xn[1] = MFMA16(xa, Wh[1][kk], xn[1]);
      xn[0] = MFMA16(xa, Wl[0][kk], xn[0]);
      xn[1] = MFMA16(xa, Wl[1][kk], xn[1]);
    }

    half8 uf0 = cvt8(pu0a,pu0b), uf1 = cvt8(pu1a,pu1b), df = cvt8(pd0a,pd0b);

    {
      int tn = t + 1; if (tn > T_STEPS-1) tn = T_STEPS-1;
      const float* un = U  + ((size_t)tn*B_ROWS + b0 + n16)*NU_;
      const float* dn = Dd + ((size_t)tn*B_ROWS + b0 + n16)*ND_;
      pu0a = *(const f32x4*)(un + q*8);
      pu0b = *(const f32x4*)(un + q*8 + 4);
      pu1a = *(const f32x4*)(un + 32 + q*8);
      pu1b = *(const f32x4*)(un + 32 + q*8 + 4);
      pd0a = *(const f32x4*)(dn + q*8);
      pd0b = *(const f32x4*)(dn + q*8 + 4);
    }

    f32x4 fu[2], fd[2];
    fu[0] = (f32x4){bus[0],bus[0],bus[0],bus[0]};
    fu[1] = (f32x4){bus[1],bus[1],bus[1],bus[1]};
    fd[0] = (f32x4){bds[0],bds[0],bds[0],bds[0]};
    fd[1] = (f32x4){bds[1],bds[1],bds[1],bds[1]};
    fu[0] = MFMA16(uf0, WuF[0][0], fu[0]);  fu[0] = MFMA16(uf1, WuF[0][1], fu[0]);
    fu[1] = MFMA16(uf0, WuF[1][0], fu[1]);  fu[1] = MFMA16(uf1, WuF[1][1], fu[1]);
    fd[0] = MFMA16(df,  WdF[0],    fd[0]);
    fd[1] = MFMA16(df,  WdF[1],    fd[1]);

    const size_t xrowbase = (size_t)t*(B_ROWS*NX_) + (size_t)b0*NX_;
    #pragma unroll
    for (int nt=0;nt<2;nt++){
      #pragma unroll
      for (int r=0;r<4;r++){
        float f  = fu[nt][r];
        float g  = fd[nt][r];
        float z  = xn[nt][r] + f + g;
        float zc = xcv[nt][r];
        float r0 = fmaxf(-1.f - z, 0.f);
        float r1 = fmaxf( z - 1.f, 0.f);
        float r2 = fmaxf(-1.f - f, 0.f);
        float r3 = fmaxf( f - 1.f, 0.f);
        float g0 = fmaxf(-1.f - g, 0.f);
        float g1 = fmaxf( g - 1.f, 0.f);
        float dz = z - zc;
        st[0]+=r0; st[1]+=r1; st[2]+=r2; st[3]+=r3;
        st[4]+=dz*dz; st[5]+=r2+r3; st[6]+=g0+g1;
        Xout[xrowbase + (size_t)(q*4+r)*NX_ + (c0+nt*16+n16)] = z;
        xw[(q*4+r)*XPITCH + c0+nt*16+n16] = (_Float16)z;
        xcv[nt][r] = z;
      }
    }
    LDSBAR();

    if (w < 4) {
      f32x4 ya = (f32x4){bys,bys,bys,bys};
      #pragma unroll
      for (int kk=0;kk<8;kk++){
        half8 xa = *(const half8*)(xw + n16*XPITCH + kk*32 + q*8);
        half8 wb = *(const half8*)(&wyl[(w*16+n16)*XPITCH + kk*32 + q*8]);
        ya = MFMA16(xa, wb, ya);
      }
      const size_t ybase = (size_t)t*(B_ROWS*NY_) + (size_t)b0*NY_ + w*16 + n16;
      #pragma unroll
      for (int r=0;r<4;r++)
        Yout[ybase + (size_t)(q*4+r)*NY_] = ya[r];
    }
  }

  #pragma unroll
  for (int off=32; off>=1; off>>=1){
    #pragma unroll
    for (int i=0;i<7;i++) st[i] += __shfl_down(st[i], off, 64);
  }
  __syncthreads();
  if (lane==0){
    #pragma unroll
    for (int i=0;i<7;i++) red[w*8+i] = st[i];
  }
  __syncthreads();
  if (tid==0){
    float s = 0.f;
    for (int ww=0; ww<8; ww++)
      for (int i=0;i<7;i++) s += red[ww*8+i];
    atomicAdd(Rout, s * (0.2f/67108864.0f));
  }
}

extern "C" void kernel_launch(void* const* d_in, const int* in_sizes, int n_in,
                              void* d_out, int out_size, void* d_ws, size_t ws_size,
                              hipStream_t stream)
{
  const float* x0=(const float*)d_in[0];
  const float* U =(const float*)d_in[1];
  const float* Dd=(const float*)d_in[2];
  const float* Wx=(const float*)d_in[3];
  const float* bx=(const float*)d_in[4];
  const float* Wu=(const float*)d_in[5];
  const float* bu=(const float*)d_in[6];
  const float* Wd=(const float*)d_in[7];
  const float* bd=(const float*)d_in[8];
  const float* Wy=(const float*)d_in[9];
  const float* by=(const float*)d_in[10];

  float* X = (float*)d_out;
  float* Y = X + (size_t)T_STEPS*B_ROWS*NX_;
  float* R = Y + (size_t)T_STEPS*B_ROWS*NY_;

  float* B0   = (float*)d_ws;                 // 65536 f32
  float* B1   = B0 + 65536;                   // 65536 f32
  float* Lend = B1 + 65536;                   // 7 * 1024*256
  float* S    = Lend + (size_t)7*B_ROWS*NX_;  // 7 * 1024*256

  hipMemsetAsync(R, 0, sizeof(float), stream);

  // G = Wx^32 (row-major) via repeated squaring; M^32 = (Wx^32)^T read
  // transposed inside combine (coalesced).
  matsq<<<dim3(256), dim3(256), 0, stream>>>(Wx, B0);  // Wx^2
  matsq<<<dim3(256), dim3(256), 0, stream>>>(B0, B1);  // Wx^4
  matsq<<<dim3(256), dim3(256), 0, stream>>>(B1, B0);  // Wx^8
  matsq<<<dim3(256), dim3(256), 0, stream>>>(B0, B1);  // Wx^16
  matsq<<<dim3(256), dim3(256), 0, stream>>>(B1, B0);  // Wx^32 -> G = B0

  phase1<<<dim3(64,7), dim3(512), 0, stream>>>(x0,U,Dd,Wx,bx,Wu,bu,Wd,bd,Lend);
  combine<<<dim3(64), dim3(512), 0, stream>>>(B0, Lend, S);
  phase2<<<dim3(64,8), dim3(512), 0, stream>>>(x0,U,Dd,Wx,bx,Wu,bu,Wd,bd,Wy,by,S,X,Y,R);
}